// Round 12
// baseline (2122.261 us; speedup 1.0000x reference)
//
#include <hip/hip_runtime.h>
#include <hip/hip_bf16.h>
#include <stdint.h>

#define NROWS 12288
#define DIM   512
#define KNBR  10

#define NC    16           // column chunks
#define CHUNK (NROWS / NC) // 768
#define TM    128          // tile dim (rows and cols)
#define CT    (CHUNK / TM) // 6 col-tiles per block
#define NRB   (NROWS / TM) // 96 row blocks
#define KS    32           // K per step
#define NK    (DIM / KS)   // 16 k-steps

// exp(-x) == +0.0f (round-nearest) for all x >= 104 (exp(-104) < 2^-150).
#define UNDERFLOW_DIST 104.0f

typedef __attribute__((ext_vector_type(8))) short s16x8;
typedef __attribute__((ext_vector_type(4))) float f32x4;
typedef unsigned int u32;

static __device__ __forceinline__ unsigned short f2bf(float x) {
  __hip_bfloat16 b = __float2bfloat16(x);
  return *reinterpret_cast<unsigned short*>(&b);
}

static __device__ __forceinline__ void gload16(const void* g, void* l) {
  __builtin_amdgcn_global_load_lds(
      (const __attribute__((address_space(1))) u32*)g,
      (__attribute__((address_space(3))) u32*)l, 16, 0, 0);
}

// Stable top-k insert: keeps list sorted by (value desc, index asc).
#define TOPK_INSERT(TV, TI, V, IDX)                                              \
  do {                                                                           \
    float _v = (V); int _i = (IDX);                                              \
    if (_v > TV[9] || (_v == TV[9] && _i < TI[9])) {                             \
      TV[9] = _v; TI[9] = _i;                                                    \
      _Pragma("unroll")                                                          \
      for (int _s = 9; _s > 0; --_s) {                                           \
        bool _sw = (TV[_s] > TV[_s-1]) ||                                        \
                   (TV[_s] == TV[_s-1] && TI[_s] < TI[_s-1]);                    \
        if (_sw) {                                                               \
          float _tf = TV[_s]; TV[_s] = TV[_s-1]; TV[_s-1] = _tf;                 \
          int   _ti = TI[_s]; TI[_s] = TI[_s-1]; TI[_s-1] = _ti;                 \
        }                                                                        \
      }                                                                          \
    }                                                                            \
  } while (0)

// ---------------- Kernel 1: norms + bf16 conversion ----------------
__global__ __launch_bounds__(256) void prep_kernel(
    const float* __restrict__ f, float* __restrict__ sq,
    unsigned short* __restrict__ fbf) {
  const int wid = threadIdx.x >> 6;
  const int lane = threadIdx.x & 63;
  const int row = blockIdx.x * 4 + wid;
  const float4* fr = (const float4*)(f + (size_t)row * DIM);
  ushort4* br = (ushort4*)(fbf + (size_t)row * DIM);
  float s = 0.f;
#pragma unroll
  for (int u = 0; u < 2; ++u) {
    float4 v = fr[u * 64 + lane];
    s += v.x * v.x + v.y * v.y + v.z * v.z + v.w * v.w;
    ushort4 h;
    h.x = f2bf(v.x); h.y = f2bf(v.y); h.z = f2bf(v.z); h.w = f2bf(v.w);
    br[u * 64 + lane] = h;
  }
#pragma unroll
  for (int off = 32; off; off >>= 1) s += __shfl_down(s, off);
  if (lane == 0) sq[row] = s;
}

// ---------------- Kernel 2: 128x128 m97-shape tile + skip epilogue ----------
// grid (96, 16). Per block: rows rt*128..+128 x chunk ch (768 cols, 6 tiles).
// Inner loop = m97 recipe: 4 waves each own a 64x64 quadrant, acc[4][4],
// BK=32, gload_lds dbuf, stage(k+1)-before-compute(k), 1 barrier/k-step ->
// 16 MFMA : 8 ds_read_b128 per wave per barrier (round 11 was 8:8 and
// LDS/barrier-bound at MfmaUtil 10.6%).
// Rounds 2-5 showed acc[4][4]+topk-in-reg spills at the ~128-160 VGPR grant;
// fix: per-thread top-10 lists PARKED IN LDS (touched only in the epilogue,
// which the round-11 underflow-skip makes rare). K-loop live set ~135 VGPR.
// LDS 49KB -> 3 blocks/CU; VGPR<=168 -> 3 waves/SIMD: both caps align.
// Swizzle (source-side, rule #21): chunk (row,p) holds k-group p^((row>>1)&3);
// reads use slot kg^((fr>>1)&3) -> bank bits {row&1, slot} distinct over 8
// rows -> 2-way residual (free). Enumerated.
__global__ __launch_bounds__(256) void gram_topk(
    const unsigned short* __restrict__ fbf, const float* __restrict__ sq,
    float2* __restrict__ part, float* __restrict__ out) {
  // staging A0|A1|B0|B1 (4 x 8KB). simf [32][130] f32 slab (16.6KB) and the
  // final merge read overlay the staging buffers (dead at those points).
  __shared__ __align__(16) char smem[32768];
  __shared__ float parkv[2560];            // per-thread top-10 values
  __shared__ unsigned short parki[2560];   // per-thread top-10 indices (<12288)
  __shared__ float sqr[TM];
  __shared__ float sqc[TM];
  float* simf = (float*)smem;

  const int t = threadIdx.x;
  const int lane = t & 63, wid = t >> 6;
  const int wr = wid >> 1, wc = wid & 1;      // wave -> 64x64 quadrant
  const int fr = lane & 15, kg = lane >> 4;   // MFMA fragment coords
  const int brow = blockIdx.x * TM;
  const int chunk = blockIdx.y;

  // Zero-fill this block's 1/1536 slice of the output.
  {
    const int bid = blockIdx.y * NRB + blockIdx.x;         // 0..1535
    const int per = NROWS * NROWS / (NRB * NC) / 4;        // f32x4 per block
    f32x4* o4 = (f32x4*)out + (size_t)bid * per;
    f32x4 z = {0.f, 0.f, 0.f, 0.f};
    for (int i = t; i < per; i += 256) o4[i] = z;
  }
  if (t < TM) sqr[t] = sq[brow + t];
#pragma unroll
  for (int s = 0; s < 10; ++s) {
    parkv[t * 10 + s] = -INFINITY;
    parki[t * 10 + s] = 0xFFFF;
  }

  // staging geometry: per k-step A,B are [128 rows][4 x 16B]. 512 chunks each;
  // thread t stages chunks t and t+256 of both. chunk c: row=c>>2, p=c&3,
  // source k-group = p ^ ((row>>1)&3). Note ((row+64)>>1)&3 == (row>>1)&3.
  const int row0 = t >> 2;
  const int sx0 = ((t & 3) ^ ((row0 >> 1) & 3)) * 8;   // elem offset in row
  const size_t gA = (size_t)row0 * DIM + sx0;
  const int d0 = wid * 1024, d1 = 4096 + wid * 1024;   // wave-uniform LDS bases
  const unsigned short* arow = fbf + (size_t)brow * DIM;
  const int slotx = (kg ^ ((fr >> 1) & 3)) * 16;       // fragment read slot

  // epilogue scan ownership (round 2/3 verified): thread owns tile row t>>1,
  // col-half t&1; its slab is mneed, its row-within-slab is srow.
  const int rt2 = t >> 1, hh = t & 1;
  const int mneed = (rt2 >> 4) & 3;
  const int srow = ((rt2 >> 6) << 4) + (rt2 & 15);

  for (int ct = 0; ct < CT; ++ct) {
    const int bcol = chunk * CHUNK + ct * TM;
    const unsigned short* bp = fbf + (size_t)bcol * DIM;
    if (t < TM) sqc[t] = sq[bcol + t];   // visible after first barrier

    f32x4 acc[4][4];
#pragma unroll
    for (int m = 0; m < 4; ++m)
#pragma unroll
      for (int n = 0; n < 4; ++n)
#pragma unroll
        for (int q = 0; q < 4; ++q) acc[m][n][q] = 0.f;

#define STAGE(KT, BUF)                                                       \
    do {                                                                     \
      char* ab_ = smem + (BUF) * 8192;                                       \
      char* bb_ = smem + 16384 + (BUF) * 8192;                               \
      gload16(arow + (KT) + gA, ab_ + d0);                                   \
      gload16(arow + (KT) + gA + 64 * DIM, ab_ + d1);                        \
      gload16(bp + (KT) + gA, bb_ + d0);                                     \
      gload16(bp + (KT) + gA + 64 * DIM, bb_ + d1);                          \
    } while (0)

    STAGE(0, 0);
    __syncthreads();   // buf0 ready; also covers sqr/sqc/park init

    for (int k = 0; k < NK; ++k) {
      if (k < NK - 1) STAGE((k + 1) * KS, (k + 1) & 1);
      const char* ab = smem + (k & 1) * 8192;
      const char* bb = smem + 16384 + (k & 1) * 8192;
      s16x8 a[4], b[4];
#pragma unroll
      for (int m = 0; m < 4; ++m)
        a[m] = *(const s16x8*)(ab + (wr * 64 + m * 16 + fr) * 64 + slotx);
#pragma unroll
      for (int n = 0; n < 4; ++n)
        b[n] = *(const s16x8*)(bb + (wc * 64 + n * 16 + fr) * 64 + slotx);
#pragma unroll
      for (int m = 0; m < 4; ++m)
#pragma unroll
        for (int n = 0; n < 4; ++n)
          acc[m][n] = __builtin_amdgcn_mfma_f32_16x16x32_bf16(a[m], b[n], acc[m][n], 0, 0, 0);
      __syncthreads();  // readers done with buf(k) + stage(k+1) drained
    }
#undef STAGE

    // Underflow vote: any dist < 104 in this 128x128 tile?
    bool under = (ct > 0);
#pragma unroll
    for (int m = 0; m < 4; ++m)
#pragma unroll
      for (int n = 0; n < 4; ++n)
#pragma unroll
        for (int q = 0; q < 4; ++q) {
          const int tr = wr * 64 + m * 16 + kg * 4 + q;
          const int tc = wc * 64 + n * 16 + fr;
          const float dist = sqr[tr] + sqc[tc] - 2.0f * acc[m][n][q];
          under = under && (dist >= UNDERFLOW_DIST);
        }
    const int skip = __syncthreads_and((int)under);  // block-uniform

    if (!skip) {
      // Full epilogue: 4 slabs of 32 rows x 128 cols over the dead staging
      // buffers; park lists updated by their owning threads.
#pragma unroll
      for (int m = 0; m < 4; ++m) {
#pragma unroll
        for (int n = 0; n < 4; ++n)
#pragma unroll
          for (int q = 0; q < 4; ++q) {
            const int rl = kg * 4 + q;            // 0..15 within band
            const int tr = wr * 64 + m * 16 + rl; // tile row
            const int tc = wc * 64 + n * 16 + fr; // tile col
            const float dist = sqr[tr] + sqc[tc] - 2.0f * acc[m][n][q];
            const float sv = ((brow + tr) == (bcol + tc)) ? 0.0f
                            : __expf(-fmaxf(dist, 0.0f));
            simf[(wr * 16 + rl) * 130 + tc] = sv;
          }
        __syncthreads();
        if (mneed == m) {
          float mv[10]; int mi[10];
#pragma unroll
          for (int s = 0; s < 10; ++s) {
            mv[s] = parkv[t * 10 + s];
            mi[s] = (int)parki[t * 10 + s];
          }
#pragma unroll
          for (int c = 0; c < 64; ++c) {
            const float v = simf[srow * 130 + hh * 64 + c];
            TOPK_INSERT(mv, mi, v, bcol + hh * 64 + c);
          }
#pragma unroll
          for (int s = 0; s < 10; ++s) {
            parkv[t * 10 + s] = mv[s];
            parki[t * 10 + s] = (unsigned short)mi[s];
          }
        }
        __syncthreads();
      }
    }
  }

  // Final: thread t<128 merges the two half-lists of row (brow+t) from park
  // and writes the chunk top-10 to the workspace.
  __syncthreads();
  if (t < TM) {
    float mv[10]; int mi[10];
#pragma unroll
    for (int s = 0; s < 10; ++s) { mv[s] = -INFINITY; mi[s] = 0x7fffffff; }
#pragma unroll
    for (int p = 0; p < 2; ++p)
#pragma unroll
      for (int s = 0; s < 10; ++s) {
        const float v = parkv[(t * 2 + p) * 10 + s];
        const int idx = (int)parki[(t * 2 + p) * 10 + s];
        TOPK_INSERT(mv, mi, v, idx);
      }
    float2* dst = part + ((size_t)(brow + t) * NC + chunk) * 10;
#pragma unroll
    for (int s = 0; s < 10; ++s) dst[s] = make_float2(mv[s], __int_as_float(mi[s]));
  }
}

// ---------------- Kernel 3: merge NC chunk lists per row, scatter ones ------
__global__ __launch_bounds__(256) void merge_scatter(
    const float2* __restrict__ part, float* __restrict__ out) {
  const int t = threadIdx.x;
  if (t >= 128) return;
  const int r = blockIdx.x * 128 + t;
  float mv[10]; int mi[10];
#pragma unroll
  for (int s = 0; s < 10; ++s) { mv[s] = -INFINITY; mi[s] = 0x7fffffff; }
  const float2* p = part + (size_t)r * NC * 10;
#pragma unroll
  for (int c = 0; c < NC * 10; ++c)
    TOPK_INSERT(mv, mi, p[c].x, __float_as_int(p[c].y));
  float* orow = out + (size_t)r * NROWS;
#pragma unroll
  for (int s = 0; s < 10; ++s) orow[mi[s]] = 1.0f;
}

// ---------------- Fallback (round-1 single-kernel path, 12.6 MB ws) ---------
__global__ __launch_bounds__(256) void knn_fallback(
    const unsigned short* __restrict__ fbf, const float* __restrict__ sq,
    float* __restrict__ out) {
  __shared__ short aT[64][32];
  __shared__ short bT[64][32];
  __shared__ float simf[5120];
  __shared__ float sqrow[64];

  const int t = threadIdx.x;
  const int lane = t & 63, wid = t >> 6;
  const int wr = wid >> 1, wc = wid & 1;
  const int fr = lane & 15, kg = lane >> 4;
  const int brow = blockIdx.x * 64;

  {
    f32x4* o4 = (f32x4*)(out + (size_t)brow * NROWS);
    const int total4 = 64 * NROWS / 4;
    f32x4 z = {0.f, 0.f, 0.f, 0.f};
    for (int i = t; i < total4; i += 256) o4[i] = z;
  }
  if (t < 64) sqrow[t] = sq[brow + t];

  float tv[10]; int ti[10];
#pragma unroll
  for (int s = 0; s < 10; ++s) { tv[s] = -INFINITY; ti[s] = 0x7fffffff; }
  const int sstage_r = t >> 2;
  const int sstage_k = (t & 3) * 8;

  for (int ctile = 0; ctile < NROWS / 64; ++ctile) {
    const int bcol = ctile * 64;
    f32x4 acc[2][2];
#pragma unroll
    for (int m = 0; m < 2; ++m)
#pragma unroll
      for (int n = 0; n < 2; ++n)
#pragma unroll
        for (int q = 0; q < 4; ++q) acc[m][n][q] = 0.f;

    for (int kt = 0; kt < DIM; kt += 32) {
      *(s16x8*)&aT[sstage_r][sstage_k] =
          *(const s16x8*)&fbf[(size_t)(brow + sstage_r) * DIM + kt + sstage_k];
      *(s16x8*)&bT[sstage_r][sstage_k] =
          *(const s16x8*)&fbf[(size_t)(bcol + sstage_r) * DIM + kt + sstage_k];
      __syncthreads();
      s16x8 a0 = *(const s16x8*)&aT[wr * 32 + fr][kg * 8];
      s16x8 a1 = *(const s16x8*)&aT[wr * 32 + 16 + fr][kg * 8];
      s16x8 b0 = *(const s16x8*)&bT[wc * 32 + fr][kg * 8];
      s16x8 b1 = *(const s16x8*)&bT[wc * 32 + 16 + fr][kg * 8];
      acc[0][0] = __builtin_amdgcn_mfma_f32_16x16x32_bf16(a0, b0, acc[0][0], 0, 0, 0);
      acc[0][1] = __builtin_amdgcn_mfma_f32_16x16x32_bf16(a0, b1, acc[0][1], 0, 0, 0);
      acc[1][0] = __builtin_amdgcn_mfma_f32_16x16x32_bf16(a1, b0, acc[1][0], 0, 0, 0);
      acc[1][1] = __builtin_amdgcn_mfma_f32_16x16x32_bf16(a1, b1, acc[1][1], 0, 0, 0);
      __syncthreads();
    }
#pragma unroll
    for (int m = 0; m < 2; ++m)
#pragma unroll
      for (int n = 0; n < 2; ++n)
#pragma unroll
        for (int q = 0; q < 4; ++q) {
          int rl = wr * 32 + m * 16 + kg * 4 + q;
          int cl = wc * 32 + n * 16 + fr;
          float dist = sqrow[rl] + sq[bcol + cl] - 2.0f * acc[m][n][q];
          float sv = ((brow + rl) == (bcol + cl)) ? 0.0f : __expf(-fmaxf(dist, 0.0f));
          simf[rl * 65 + cl] = sv;
        }
    __syncthreads();
    {
      const int c0 = wid * 16;
#pragma unroll
      for (int c = 0; c < 16; ++c) {
        float v = simf[lane * 65 + c0 + c];
        TOPK_INSERT(tv, ti, v, bcol + c0 + c);
      }
    }
    __syncthreads();
  }
#pragma unroll
  for (int s = 0; s < 10; ++s) {
    simf[(lane * 4 + wid) * 20 + s * 2]     = tv[s];
    simf[(lane * 4 + wid) * 20 + s * 2 + 1] = __int_as_float(ti[s]);
  }
  __syncthreads();
  if (t < 64) {
    float mv[10]; int mi[10];
#pragma unroll
    for (int s = 0; s < 10; ++s) { mv[s] = -INFINITY; mi[s] = 0x7fffffff; }
#pragma unroll
    for (int p = 0; p < 4; ++p)
#pragma unroll
      for (int s = 0; s < 10; ++s) {
        float v = simf[(t * 4 + p) * 20 + s * 2];
        int idx = __float_as_int(simf[(t * 4 + p) * 20 + s * 2 + 1]);
        TOPK_INSERT(mv, mi, v, idx);
      }
    float* orow = out + (size_t)(brow + t) * NROWS;
#pragma unroll
    for (int s = 0; s < 10; ++s) orow[mi[s]] = 1.0f;
  }
}

extern "C" void kernel_launch(void* const* d_in, const int* in_sizes, int n_in,
                              void* d_out, int out_size, void* d_ws, size_t ws_size,
                              hipStream_t stream) {
  const float* f = (const float*)d_in[0];
  float* out = (float*)d_out;

  const size_t sq_bytes   = (size_t)NROWS * sizeof(float);          // 49152
  const size_t fbf_bytes  = (size_t)NROWS * DIM * sizeof(unsigned short);
  const size_t part_bytes = (size_t)NROWS * NC * 10 * sizeof(float2);

  float* sq = (float*)d_ws;
  unsigned short* fbf = (unsigned short*)((char*)d_ws + sq_bytes);
  float2* part = (float2*)((char*)d_ws + sq_bytes + fbf_bytes);

  if (ws_size >= sq_bytes + fbf_bytes + part_bytes) {
    prep_kernel<<<NROWS / 4, 256, 0, stream>>>(f, sq, fbf);
    gram_topk<<<dim3(NRB, NC), 256, 0, stream>>>(fbf, sq, part, out);
    merge_scatter<<<NROWS / 128, 256, 0, stream>>>(part, out);
  } else if (ws_size >= sq_bytes + fbf_bytes) {
    prep_kernel<<<NROWS / 4, 256, 0, stream>>>(f, sq, fbf);
    knn_fallback<<<NROWS / 64, 256, 0, stream>>>(fbf, sq, out);
  }
}

// Round 13
// 1303.530 us; speedup vs baseline: 1.6281x; 1.6281x over previous
//
#include <hip/hip_runtime.h>
#include <hip/hip_bf16.h>
#include <stdint.h>

#define NROWS 12288
#define DIM   512
#define KNBR  10

#define NC    16           // column chunks
#define CHUNK (NROWS / NC) // 768
#define BM    128          // tile rows
#define BN    64           // tile cols
#define CT    (CHUNK / BN) // 12 col-tiles per block
#define NRB   (NROWS / BM) // 96 row blocks
#define BK    64           // K per barrier step
#define NK    (DIM / BK)   // 8 k-steps

// exp(-x) == +0.0f (round-nearest) for all x >= 104 (exp(-104) < 2^-150).
#define UNDERFLOW_DIST 104.0f

typedef __attribute__((ext_vector_type(8))) short s16x8;
typedef __attribute__((ext_vector_type(4))) float f32x4;
typedef unsigned int u32;

static __device__ __forceinline__ unsigned short f2bf(float x) {
  __hip_bfloat16 b = __float2bfloat16(x);
  return *reinterpret_cast<unsigned short*>(&b);
}

static __device__ __forceinline__ void gload16(const void* g, void* l) {
  __builtin_amdgcn_global_load_lds(
      (const __attribute__((address_space(1))) u32*)g,
      (__attribute__((address_space(3))) u32*)l, 16, 0, 0);
}

// Stable top-k insert: keeps list sorted by (value desc, index asc).
#define TOPK_INSERT(TV, TI, V, IDX)                                              \
  do {                                                                           \
    float _v = (V); int _i = (IDX);                                              \
    if (_v > TV[9] || (_v == TV[9] && _i < TI[9])) {                             \
      TV[9] = _v; TI[9] = _i;                                                    \
      _Pragma("unroll")                                                          \
      for (int _s = 9; _s > 0; --_s) {                                           \
        bool _sw = (TV[_s] > TV[_s-1]) ||                                        \
                   (TV[_s] == TV[_s-1] && TI[_s] < TI[_s-1]);                    \
        if (_sw) {                                                               \
          float _tf = TV[_s]; TV[_s] = TV[_s-1]; TV[_s-1] = _tf;                 \
          int   _ti = TI[_s]; TI[_s] = TI[_s-1]; TI[_s-1] = _ti;                 \
        }                                                                        \
      }                                                                          \
    }                                                                            \
  } while (0)

// ---------------- Kernel 1: norms + bf16 conversion ----------------
__global__ __launch_bounds__(256) void prep_kernel(
    const float* __restrict__ f, float* __restrict__ sq,
    unsigned short* __restrict__ fbf) {
  const int wid = threadIdx.x >> 6;
  const int lane = threadIdx.x & 63;
  const int row = blockIdx.x * 4 + wid;
  const float4* fr = (const float4*)(f + (size_t)row * DIM);
  ushort4* br = (ushort4*)(fbf + (size_t)row * DIM);
  float s = 0.f;
#pragma unroll
  for (int u = 0; u < 2; ++u) {
    float4 v = fr[u * 64 + lane];
    s += v.x * v.x + v.y * v.y + v.z * v.z + v.w * v.w;
    ushort4 h;
    h.x = f2bf(v.x); h.y = f2bf(v.y); h.z = f2bf(v.z); h.w = f2bf(v.w);
    br[u * 64 + lane] = h;
  }
#pragma unroll
  for (int off = 32; off; off >>= 1) s += __shfl_down(s, off);
  if (lane == 0) sq[row] = s;
}

// ---------------- Kernel 2: 128x64 tile, acc[4][2], skip epilogue -----------
// grid (96, 16). Block: rows rt*128..+128 x chunk ch (768 cols, 12 tiles of 64).
// Per-wave sub-tile 64x32 -> acc[4][2] = 32 VGPR: the ONLY larger-than-32x32
// shape hipcc allocates spill-free in this kernel family (r6: VGPR 136, no
// scratch; acc[4][4] spilled in r2/r3/r5/r12 under every launch-bound).
// Per K=64 step per wave: 12 ds_read_b128 : 16 MFMA (r11 was 8:8) and half
// the barriers per output. All r11 levers kept: gload_lds + source-side XOR
// swizzle (rule #21), dbuf + stage(k+1)-before-compute(k), underflow-skip.
__global__ __launch_bounds__(256) void gram_topk(
    const unsigned short* __restrict__ fbf, const float* __restrict__ sq,
    float2* __restrict__ part, float* __restrict__ out) {
  // smem: A0 @0 (16KB) | A1 @16K | B0 @32K (8KB) | B1 @40K. simf [32][67] f32
  // slab (8576B) and the merge dump (20480B) overlay dead staging buffers.
  __shared__ __align__(16) char smem[49152];
  __shared__ float sqr[BM];
  __shared__ float sqc[BN];
  float* simf = (float*)smem;

  const int t = threadIdx.x;
  const int lane = t & 63, wid = t >> 6;
  const int wr = wid >> 1, wc = wid & 1;      // wave -> 64-row half, 32-col half
  const int fr = lane & 15, kg = lane >> 4;   // MFMA fragment coords
  const int brow = blockIdx.x * BM;
  const int chunk = blockIdx.y;

  // Zero-fill this block's 1/1536 slice of the output.
  {
    const int bid = blockIdx.y * NRB + blockIdx.x;         // 0..1535
    const int per = NROWS * NROWS / (NRB * NC) / 4;        // f32x4 per block
    f32x4* o4 = (f32x4*)out + (size_t)bid * per;
    f32x4 z = {0.f, 0.f, 0.f, 0.f};
    for (int i = t; i < per; i += 256) o4[i] = z;
  }
  if (t < BM) sqr[t] = sq[brow + t];

  float tv[10]; int ti[10];
#pragma unroll
  for (int s = 0; s < 10; ++s) { tv[s] = -INFINITY; ti[s] = 0x7fffffff; }

  // staging: rows are 128B (8 x 16B slots); chunk (row, p) holds source
  // k-group p ^ (row&7). Thread t stages chunk i*256+t of each call:
  // row = i*32 + (t>>3), slot = t&7 -> swizzle term identical across calls.
  const size_t gA0 = (size_t)(t >> 3) * DIM + (((t & 7) ^ ((t >> 3) & 7)) * 8);
  const int dB = wid * 1024;   // wave-uniform LDS base (+lane*16 by HW)
  const unsigned short* arow = fbf + (size_t)brow * DIM;
  // fragment read: stored k-group g sits at slot g^(row&7); row&7 == fr&7.
  const int frx = fr & 7;

  // epilogue scan ownership (r6-verified): thread owns tile row rt2=t>>1,
  // col half hh=t&1; slab index mneed, row-within-slab srow.
  const int rt2 = t >> 1, hh = t & 1;
  const int mneed = (rt2 >> 4) & 3;
  const int srow = ((rt2 >> 6) << 4) + (rt2 & 15);

  for (int ct = 0; ct < CT; ++ct) {
    const int bcol = chunk * CHUNK + ct * BN;
    const unsigned short* bp = fbf + (size_t)bcol * DIM;
    if (t < BN) sqc[t] = sq[bcol + t];   // visible after first barrier

    f32x4 acc[4][2];
#pragma unroll
    for (int m = 0; m < 4; ++m)
#pragma unroll
      for (int n = 0; n < 2; ++n)
#pragma unroll
        for (int q = 0; q < 4; ++q) acc[m][n][q] = 0.f;

    // stage(kt, buf): A = 4 calls (128 rows x 128B), B = 2 calls (64 rows)
#define STAGE(KT, BUF)                                                       \
    do {                                                                     \
      char* ab_ = smem + (BUF) * 16384;                                      \
      char* bb_ = smem + 32768 + (BUF) * 8192;                               \
      gload16(arow + (KT) + gA0,                ab_ + dB);                   \
      gload16(arow + (KT) + gA0 + 32 * DIM,     ab_ + 4096 + dB);            \
      gload16(arow + (KT) + gA0 + 64 * DIM,     ab_ + 8192 + dB);            \
      gload16(arow + (KT) + gA0 + 96 * DIM,     ab_ + 12288 + dB);           \
      gload16(bp + (KT) + gA0,                  bb_ + dB);                   \
      gload16(bp + (KT) + gA0 + 32 * DIM,       bb_ + 4096 + dB);            \
    } while (0)

    STAGE(0, 0);
    __syncthreads();   // buf0 ready (vmcnt drained); also covers sqr/sqc init

    for (int k = 0; k < NK; ++k) {
      if (k < NK - 1) STAGE((k + 1) * BK, (k + 1) & 1);
      const char* ab = smem + (k & 1) * 16384;
      const char* bb = smem + 32768 + (k & 1) * 8192;
#pragma unroll
      for (int h = 0; h < 2; ++h) {
        const int ob = (((h << 2) | kg) ^ frx) << 4;
        s16x8 a[4], b[2];
#pragma unroll
        for (int m = 0; m < 4; ++m)
          a[m] = *(const s16x8*)(ab + (wr * 64 + m * 16 + fr) * 128 + ob);
#pragma unroll
        for (int n = 0; n < 2; ++n)
          b[n] = *(const s16x8*)(bb + (wc * 32 + n * 16 + fr) * 128 + ob);
#pragma unroll
        for (int m = 0; m < 4; ++m)
#pragma unroll
          for (int n = 0; n < 2; ++n)
            acc[m][n] = __builtin_amdgcn_mfma_f32_16x16x32_bf16(a[m], b[n], acc[m][n], 0, 0, 0);
      }
      __syncthreads();  // readers done with buf(k) + stage(k+1) drained
    }
#undef STAGE

    // Per-thread column norms, register-hoisted.
    const float sqc0 = sqc[wc * 32 + fr];
    const float sqc1 = sqc[wc * 32 + 16 + fr];

    // Underflow vote: any dist < 104 in this 128x64 tile?
    bool under = (ct > 0);
#pragma unroll
    for (int m = 0; m < 4; ++m)
#pragma unroll
      for (int n = 0; n < 2; ++n) {
        const float sqcn = n ? sqc1 : sqc0;
#pragma unroll
        for (int q = 0; q < 4; ++q) {
          const int tr = wr * 64 + m * 16 + kg * 4 + q;
          const float dist = sqr[tr] + sqcn - 2.0f * acc[m][n][q];
          under = under && (dist >= UNDERFLOW_DIST);
        }
      }
    const int skip = __syncthreads_and((int)under);  // block-uniform

    if (!skip) {
      // Full epilogue: 4 slabs of 32 rows x 64 cols over dead staging bufs.
      // Slab m holds rows {m*16..+15} u {64+m*16..+15} as slab-rows wr*16+rl.
#pragma unroll
      for (int m = 0; m < 4; ++m) {
#pragma unroll
        for (int n = 0; n < 2; ++n)
#pragma unroll
          for (int q = 0; q < 4; ++q) {
            const int rl = kg * 4 + q;            // 0..15 within band
            const int tr = wr * 64 + m * 16 + rl; // tile row
            const int tc = wc * 32 + n * 16 + fr; // tile col
            const float dist = sqr[tr] + (n ? sqc1 : sqc0) - 2.0f * acc[m][n][q];
            const float sv = ((brow + tr) == (bcol + tc)) ? 0.0f
                            : __expf(-fmaxf(dist, 0.0f));
            simf[(wr * 16 + rl) * 67 + tc] = sv;
          }
        __syncthreads();
        if (mneed == m) {
#pragma unroll
          for (int c = 0; c < 32; ++c) {
            const float v = simf[srow * 67 + hh * 32 + c];
            TOPK_INSERT(tv, ti, v, bcol + hh * 32 + c);
          }
        }
        __syncthreads();
      }
    }
  }

  // Dump the 2 half-lists per row, merge (thread t<128 owns row brow+t),
  // write the row's chunk top-10 to the workspace.
#pragma unroll
  for (int s = 0; s < 10; ++s) {
    simf[t * 20 + s * 2]     = tv[s];
    simf[t * 20 + s * 2 + 1] = __int_as_float(ti[s]);
  }
  __syncthreads();
  if (t < BM) {
    float mv[10]; int mi[10];
#pragma unroll
    for (int s = 0; s < 10; ++s) { mv[s] = -INFINITY; mi[s] = 0x7fffffff; }
#pragma unroll
    for (int p = 0; p < 2; ++p)
#pragma unroll
      for (int s = 0; s < 10; ++s) {
        const float v = simf[(t * 2 + p) * 20 + s * 2];
        const int idx = __float_as_int(simf[(t * 2 + p) * 20 + s * 2 + 1]);
        TOPK_INSERT(mv, mi, v, idx);
      }
    float2* dst = part + ((size_t)(brow + t) * NC + chunk) * 10;
#pragma unroll
    for (int s = 0; s < 10; ++s) dst[s] = make_float2(mv[s], __int_as_float(mi[s]));
  }
}

// ---------------- Kernel 3: merge NC chunk lists per row, scatter ones ------
__global__ __launch_bounds__(256) void merge_scatter(
    const float2* __restrict__ part, float* __restrict__ out) {
  const int t = threadIdx.x;
  if (t >= 128) return;
  const int r = blockIdx.x * 128 + t;
  float mv[10]; int mi[10];
#pragma unroll
  for (int s = 0; s < 10; ++s) { mv[s] = -INFINITY; mi[s] = 0x7fffffff; }
  const float2* p = part + (size_t)r * NC * 10;
#pragma unroll
  for (int c = 0; c < NC * 10; ++c)
    TOPK_INSERT(mv, mi, p[c].x, __float_as_int(p[c].y));
  float* orow = out + (size_t)r * NROWS;
#pragma unroll
  for (int s = 0; s < 10; ++s) orow[mi[s]] = 1.0f;
}

// ---------------- Fallback (round-1 single-kernel path, 12.6 MB ws) ---------
__global__ __launch_bounds__(256) void knn_fallback(
    const unsigned short* __restrict__ fbf, const float* __restrict__ sq,
    float* __restrict__ out) {
  __shared__ short aT[64][32];
  __shared__ short bT[64][32];
  __shared__ float simf[5120];
  __shared__ float sqrow[64];

  const int t = threadIdx.x;
  const int lane = t & 63, wid = t >> 6;
  const int wr = wid >> 1, wc = wid & 1;
  const int fr = lane & 15, kg = lane >> 4;
  const int brow = blockIdx.x * 64;

  {
    f32x4* o4 = (f32x4*)(out + (size_t)brow * NROWS);
    const int total4 = 64 * NROWS / 4;
    f32x4 z = {0.f, 0.f, 0.f, 0.f};
    for (int i = t; i < total4; i += 256) o4[i] = z;
  }
  if (t < 64) sqrow[t] = sq[brow + t];

  float tv[10]; int ti[10];
#pragma unroll
  for (int s = 0; s < 10; ++s) { tv[s] = -INFINITY; ti[s] = 0x7fffffff; }
  const int sstage_r = t >> 2;
  const int sstage_k = (t & 3) * 8;

  for (int ctile = 0; ctile < NROWS / 64; ++ctile) {
    const int bcol = ctile * 64;
    f32x4 acc[2][2];
#pragma unroll
    for (int m = 0; m < 2; ++m)
#pragma unroll
      for (int n = 0; n < 2; ++n)
#pragma unroll
        for (int q = 0; q < 4; ++q) acc[m][n][q] = 0.f;

    for (int kt = 0; kt < DIM; kt += 32) {
      *(s16x8*)&aT[sstage_r][sstage_k] =
          *(const s16x8*)&fbf[(size_t)(brow + sstage_r) * DIM + kt + sstage_k];
      *(s16x8*)&bT[sstage_r][sstage_k] =
          *(const s16x8*)&fbf[(size_t)(bcol + sstage_r) * DIM + kt + sstage_k];
      __syncthreads();
      s16x8 a0 = *(const s16x8*)&aT[wr * 32 + fr][kg * 8];
      s16x8 a1 = *(const s16x8*)&aT[wr * 32 + 16 + fr][kg * 8];
      s16x8 b0 = *(const s16x8*)&bT[wc * 32 + fr][kg * 8];
      s16x8 b1 = *(const s16x8*)&bT[wc * 32 + 16 + fr][kg * 8];
      acc[0][0] = __builtin_amdgcn_mfma_f32_16x16x32_bf16(a0, b0, acc[0][0], 0, 0, 0);
      acc[0][1] = __builtin_amdgcn_mfma_f32_16x16x32_bf16(a0, b1, acc[0][1], 0, 0, 0);
      acc[1][0] = __builtin_amdgcn_mfma_f32_16x16x32_bf16(a1, b0, acc[1][0], 0, 0, 0);
      acc[1][1] = __builtin_amdgcn_mfma_f32_16x16x32_bf16(a1, b1, acc[1][1], 0, 0, 0);
      __syncthreads();
    }
#pragma unroll
    for (int m = 0; m < 2; ++m)
#pragma unroll
      for (int n = 0; n < 2; ++n)
#pragma unroll
        for (int q = 0; q < 4; ++q) {
          int rl = wr * 32 + m * 16 + kg * 4 + q;
          int cl = wc * 32 + n * 16 + fr;
          float dist = sqrow[rl] + sq[bcol + cl] - 2.0f * acc[m][n][q];
          float sv = ((brow + rl) == (bcol + cl)) ? 0.0f : __expf(-fmaxf(dist, 0.0f));
          simf[rl * 65 + cl] = sv;
        }
    __syncthreads();
    {
      const int c0 = wid * 16;
#pragma unroll
      for (int c = 0; c < 16; ++c) {
        float v = simf[lane * 65 + c0 + c];
        TOPK_INSERT(tv, ti, v, bcol + c0 + c);
      }
    }
    __syncthreads();
  }
#pragma unroll
  for (int s = 0; s < 10; ++s) {
    simf[(lane * 4 + wid) * 20 + s * 2]     = tv[s];
    simf[(lane * 4 + wid) * 20 + s * 2 + 1] = __int_as_float(ti[s]);
  }
  __syncthreads();
  if (t < 64) {
    float mv[10]; int mi[10];
#pragma unroll
    for (int s = 0; s < 10; ++s) { mv[s] = -INFINITY; mi[s] = 0x7fffffff; }
#pragma unroll
    for (int p = 0; p < 4; ++p)
#pragma unroll
      for (int s = 0; s < 10; ++s) {
        float v = simf[(t * 4 + p) * 20 + s * 2];
        int idx = __float_as_int(simf[(t * 4 + p) * 20 + s * 2 + 1]);
        TOPK_INSERT(mv, mi, v, idx);
      }
    float* orow = out + (size_t)(brow + t) * NROWS;
#pragma unroll
    for (int s = 0; s < 10; ++s) orow[mi[s]] = 1.0f;
  }
}

extern "C" void kernel_launch(void* const* d_in, const int* in_sizes, int n_in,
                              void* d_out, int out_size, void* d_ws, size_t ws_size,
                              hipStream_t stream) {
  const float* f = (const float*)d_in[0];
  float* out = (float*)d_out;

  const size_t sq_bytes   = (size_t)NROWS * sizeof(float);          // 49152
  const size_t fbf_bytes  = (size_t)NROWS * DIM * sizeof(unsigned short);
  const size_t part_bytes = (size_t)NROWS * NC * 10 * sizeof(float2);

  float* sq = (float*)d_ws;
  unsigned short* fbf = (unsigned short*)((char*)d_ws + sq_bytes);
  float2* part = (float2*)((char*)d_ws + sq_bytes + fbf_bytes);

  if (ws_size >= sq_bytes + fbf_bytes + part_bytes) {
    prep_kernel<<<NROWS / 4, 256, 0, stream>>>(f, sq, fbf);
    gram_topk<<<dim3(NRB, NC), 256, 0, stream>>>(fbf, sq, part, out);
    merge_scatter<<<NROWS / 128, 256, 0, stream>>>(part, out);
  } else if (ws_size >= sq_bytes + fbf_bytes) {
    prep_kernel<<<NROWS / 4, 256, 0, stream>>>(f, sq, fbf);
    knn_fallback<<<NROWS / 64, 256, 0, stream>>>(fbf, sq, out);
  }
}

// Round 14
// 574.941 us; speedup vs baseline: 3.6913x; 2.2672x over previous
//
#include <hip/hip_runtime.h>
#include <hip/hip_bf16.h>
#include <stdint.h>

#define NROWS 12288
#define DIM   512
#define KNBR  10

#define NC    8            // column chunks
#define CHUNK (NROWS / NC) // 1536
#define BT    64           // tile (rows and cols)
#define CT    (CHUNK / BT) // 24 col-tiles per block
#define NRB   (NROWS / BT) // 192 row blocks
#define KS    32           // K per pipeline step
#define KST   (DIM / KS)   // 16 k-steps

// exp(-x) == +0.0f (round-nearest) for all x >= 104 (exp(-104) < 2^-150).
#define UNDERFLOW_DIST 104.0f

typedef __attribute__((ext_vector_type(8))) short s16x8;
typedef __attribute__((ext_vector_type(4))) float f32x4;
typedef unsigned int u32;

static __device__ __forceinline__ unsigned short f2bf(float x) {
  __hip_bfloat16 b = __float2bfloat16(x);
  return *reinterpret_cast<unsigned short*>(&b);
}

static __device__ __forceinline__ void gload16(const void* g, void* l) {
  __builtin_amdgcn_global_load_lds(
      (const __attribute__((address_space(1))) u32*)g,
      (__attribute__((address_space(3))) u32*)l, 16, 0, 0);
}

// Stable top-k insert: keeps list sorted by (value desc, index asc).
#define TOPK_INSERT(TV, TI, V, IDX)                                              \
  do {                                                                           \
    float _v = (V); int _i = (IDX);                                              \
    if (_v > TV[9] || (_v == TV[9] && _i < TI[9])) {                             \
      TV[9] = _v; TI[9] = _i;                                                    \
      _Pragma("unroll")                                                          \
      for (int _s = 9; _s > 0; --_s) {                                           \
        bool _sw = (TV[_s] > TV[_s-1]) ||                                        \
                   (TV[_s] == TV[_s-1] && TI[_s] < TI[_s-1]);                    \
        if (_sw) {                                                               \
          float _tf = TV[_s]; TV[_s] = TV[_s-1]; TV[_s-1] = _tf;                 \
          int   _ti = TI[_s]; TI[_s] = TI[_s-1]; TI[_s-1] = _ti;                 \
        }                                                                        \
      }                                                                          \
    }                                                                            \
  } while (0)

// ---------------- Kernel 1: norms + bf16 conversion ----------------
__global__ __launch_bounds__(256) void prep_kernel(
    const float* __restrict__ f, float* __restrict__ sq,
    unsigned short* __restrict__ fbf) {
  const int wid = threadIdx.x >> 6;
  const int lane = threadIdx.x & 63;
  const int row = blockIdx.x * 4 + wid;
  const float4* fr = (const float4*)(f + (size_t)row * DIM);
  ushort4* br = (ushort4*)(fbf + (size_t)row * DIM);
  float s = 0.f;
#pragma unroll
  for (int u = 0; u < 2; ++u) {
    float4 v = fr[u * 64 + lane];
    s += v.x * v.x + v.y * v.y + v.z * v.z + v.w * v.w;
    ushort4 h;
    h.x = f2bf(v.x); h.y = f2bf(v.y); h.z = f2bf(v.z); h.w = f2bf(v.w);
    br[u * 64 + lane] = h;
  }
#pragma unroll
  for (int off = 32; off; off >>= 1) s += __shfl_down(s, off);
  if (lane == 0) sq[row] = s;
}

// ---------------- Kernel 2: 64x64 tile, 3-buffer counted-vmcnt pipeline -----
// grid (192, 8) = r11's verified geometry (584 us). ONE structural change:
// the k-loop no longer uses __syncthreads (whose implicit vmcnt(0) drained
// the just-issued prefetch every step = ~80% of r11's cycles by the model).
// 3 LDS buffer-slices, STAGE(k+2) issued at step k, then
//   s_waitcnt vmcnt(2)   -> my STAGE(k+1) loads landed (k+2's 2 stay in flight)
//   s_barrier            -> everyone's landed (vmcnt is per-wave)
// Issue-to-use = 2 compute phases (~400+ cy) > L2 latency -> no stall.
// WAR safety: STAGE(k+2) overwrites buf((k+2)%3) == buf((k-1)%3), whose reads
// all completed before barrier(k-1) (ds_read results are consumed by MFMA
// issue, which precedes the barrier in program order).
// Swizzle (64B rows, 4 slots): chunk(row,slot) holds kgroup slot^((row>>1)&3);
// reads use slot kg^((fr>>1)&3) -> 8 banks over 16 lanes = 2-way (free).
__global__ __launch_bounds__(256) void gram_topk(
    const unsigned short* __restrict__ fbf, const float* __restrict__ sq,
    float2* __restrict__ part, float* __restrict__ out) {
  // smem: A slices @0,4096,8192 ; B slices @12288,16384,20480 (24KB total).
  // simf [64][66] f32 (16896B) and merge dump (20480B) overlay the buffers.
  __shared__ __align__(16) char smem[24576];
  __shared__ float sqrow[BT];
  __shared__ float sqcs[BT];
  float* simf = (float*)smem;

  const int t = threadIdx.x;
  const int lane = t & 63, wid = t >> 6;
  const int wr = wid >> 1, wc = wid & 1;      // wave -> 32x32 quadrant
  const int fr = lane & 15, kg = lane >> 4;   // MFMA fragment coords
  const int brow = blockIdx.x * BT;
  const int chunk = blockIdx.y;

  // Zero-fill this block's 1/1536 slice of the output.
  {
    const int bid = blockIdx.y * NRB + blockIdx.x;         // 0..1535
    const int per = NROWS * NROWS / (NRB * NC) / 4;        // f32x4 per block
    f32x4* o4 = (f32x4*)out + (size_t)bid * per;
    f32x4 z = {0.f, 0.f, 0.f, 0.f};
    for (int i = t; i < per; i += 256) o4[i] = z;
  }
  if (t < BT) sqrow[t] = sq[brow + t];

  float tv[10]; int ti[10];
#pragma unroll
  for (int s = 0; s < 10; ++s) { tv[s] = -INFINITY; ti[s] = 0x7fffffff; }

  // staging: per slice, A (and B) = [64 rows][4 x 16B slots] = 4KB = 256
  // chunks; thread t stages chunk t: row=t>>2, slot=t&3, source k-group
  // = slot ^ ((row>>1)&3). LDS dest linear (chunk t at byte t*16).
  const int srow0 = t >> 2;
  const size_t gOff = (size_t)srow0 * DIM + (((t & 3) ^ ((srow0 >> 1) & 3)) * 8);
  const int dB = wid * 1024;   // wave-uniform LDS base (+lane*16 by HW)
  const unsigned short* arow = fbf + (size_t)brow * DIM;
  // fragment read slot: kgroup kg stored at slot kg^((row>>1)&3); for rows
  // wr*32+fr / +16, ((row>>1)&3) == ((fr>>1)&3).
  const int slotx = (kg ^ ((fr >> 1) & 3)) * 16;

  for (int ct = 0; ct < CT; ++ct) {
    const int bcol = chunk * CHUNK + ct * BT;
    const unsigned short* bp = fbf + (size_t)bcol * DIM;
    if (t < BT) sqcs[t] = sq[bcol + t];   // oldest vmem op; drained by vmcnt(2)

    f32x4 acc[2][2];
#pragma unroll
    for (int m = 0; m < 2; ++m)
#pragma unroll
      for (int n = 0; n < 2; ++n)
#pragma unroll
        for (int q = 0; q < 4; ++q) acc[m][n][q] = 0.f;

#define STAGE(KT, BUF)                                                       \
    do {                                                                     \
      gload16(arow + (KT) + gOff, smem + (BUF) * 4096 + dB);                 \
      gload16(bp + (KT) + gOff, smem + 12288 + (BUF) * 4096 + dB);           \
    } while (0)

    STAGE(0, 0);
    STAGE(KS, 1);
    asm volatile("s_waitcnt vmcnt(2)" ::: "memory");  // slice 0 landed (mine)
    __builtin_amdgcn_s_barrier();                      // ... and everyone's
    __builtin_amdgcn_sched_barrier(0);

#pragma unroll
    for (int k = 0; k < KST; ++k) {
      const char* ab = smem + (k % 3) * 4096;
      const char* bb = smem + 12288 + (k % 3) * 4096;
      s16x8 a0 = *(const s16x8*)(ab + (wr * 32 + fr) * 64 + slotx);
      s16x8 a1 = *(const s16x8*)(ab + (wr * 32 + 16 + fr) * 64 + slotx);
      s16x8 b0 = *(const s16x8*)(bb + (wc * 32 + fr) * 64 + slotx);
      s16x8 b1 = *(const s16x8*)(bb + (wc * 32 + 16 + fr) * 64 + slotx);
      acc[0][0] = __builtin_amdgcn_mfma_f32_16x16x32_bf16(a0, b0, acc[0][0], 0, 0, 0);
      acc[0][1] = __builtin_amdgcn_mfma_f32_16x16x32_bf16(a0, b1, acc[0][1], 0, 0, 0);
      acc[1][0] = __builtin_amdgcn_mfma_f32_16x16x32_bf16(a1, b0, acc[1][0], 0, 0, 0);
      acc[1][1] = __builtin_amdgcn_mfma_f32_16x16x32_bf16(a1, b1, acc[1][1], 0, 0, 0);
      if (k < KST - 2) {
        STAGE((k + 2) * KS, (k + 2) % 3);   // overwrites buf((k-1)%3): safe
        asm volatile("s_waitcnt vmcnt(2)" ::: "memory");  // STAGE(k+1) landed
      } else {
        asm volatile("s_waitcnt vmcnt(0)" ::: "memory");  // tail: drain all
      }
      __builtin_amdgcn_s_barrier();
      __builtin_amdgcn_sched_barrier(0);
    }
#undef STAGE

    // Per-thread column norms (from LDS; sqcs visible since prologue barrier).
    const float sqc0 = sqcs[wc * 32 + fr];
    const float sqc1 = sqcs[wc * 32 + 16 + fr];

    // Underflow vote: any dist < 104 in this tile?
    bool under = (ct > 0);
#pragma unroll
    for (int m = 0; m < 2; ++m)
#pragma unroll
      for (int n = 0; n < 2; ++n) {
        const float sqcn = n ? sqc1 : sqc0;
#pragma unroll
        for (int q = 0; q < 4; ++q) {
          const int rl = wr * 32 + m * 16 + kg * 4 + q;
          const float dist = sqrow[rl] + sqcn - 2.0f * acc[m][n][q];
          under = under && (dist >= UNDERFLOW_DIST);
        }
      }
    const int skip = __syncthreads_and((int)under);  // block-uniform

    if (!skip) {
      // Full epilogue (rare): dist -> sim, LDS tile (overlays buffers), scan.
#pragma unroll
      for (int m = 0; m < 2; ++m)
#pragma unroll
        for (int n = 0; n < 2; ++n)
#pragma unroll
          for (int q = 0; q < 4; ++q) {
            int rl = wr * 32 + m * 16 + kg * 4 + q;
            int cl = wc * 32 + n * 16 + fr;
            float dist = sqrow[rl] + (n ? sqc1 : sqc0) - 2.0f * acc[m][n][q];
            float sv = ((brow + rl) == (bcol + cl)) ? 0.0f
                       : __expf(-fmaxf(dist, 0.0f));
            simf[rl * 66 + cl] = sv;
          }
      __syncthreads();
      {
        const int c0 = wid * 16;
#pragma unroll
        for (int c = 0; c < 16; ++c) {
          float v = simf[lane * 66 + c0 + c];
          TOPK_INSERT(tv, ti, v, bcol + c0 + c);
        }
      }
      __syncthreads();   // scan done before buffers are re-staged next ct
    }
  }

  // Dump 4 partial lists per row, merge (thread t<64 owns row brow+t),
  // write the row's chunk top-10 to the workspace.
#pragma unroll
  for (int s = 0; s < 10; ++s) {
    simf[(lane * 4 + wid) * 20 + s * 2]     = tv[s];
    simf[(lane * 4 + wid) * 20 + s * 2 + 1] = __int_as_float(ti[s]);
  }
  __syncthreads();
  if (t < BT) {
    float mv[10]; int mi[10];
#pragma unroll
    for (int s = 0; s < 10; ++s) { mv[s] = -INFINITY; mi[s] = 0x7fffffff; }
#pragma unroll
    for (int p = 0; p < 4; ++p)
#pragma unroll
      for (int s = 0; s < 10; ++s) {
        float v = simf[(t * 4 + p) * 20 + s * 2];
        int idx = __float_as_int(simf[(t * 4 + p) * 20 + s * 2 + 1]);
        TOPK_INSERT(mv, mi, v, idx);
      }
    float2* dst = part + ((size_t)(brow + t) * NC + chunk) * 10;
#pragma unroll
    for (int s = 0; s < 10; ++s) dst[s] = make_float2(mv[s], __int_as_float(mi[s]));
  }
}

// ---------------- Kernel 3: merge NC chunk lists per row, scatter ones ------
__global__ __launch_bounds__(256) void merge_scatter(
    const float2* __restrict__ part, float* __restrict__ out) {
  const int t = threadIdx.x;
  if (t >= 128) return;
  const int r = blockIdx.x * 128 + t;
  float mv[10]; int mi[10];
#pragma unroll
  for (int s = 0; s < 10; ++s) { mv[s] = -INFINITY; mi[s] = 0x7fffffff; }
  const float2* p = part + (size_t)r * NC * 10;
#pragma unroll
  for (int c = 0; c < NC * 10; ++c)
    TOPK_INSERT(mv, mi, p[c].x, __float_as_int(p[c].y));
  float* orow = out + (size_t)r * NROWS;
#pragma unroll
  for (int s = 0; s < 10; ++s) orow[mi[s]] = 1.0f;
}

// ---------------- Fallback (round-1 single-kernel path, 12.6 MB ws) ---------
__global__ __launch_bounds__(256) void knn_fallback(
    const unsigned short* __restrict__ fbf, const float* __restrict__ sq,
    float* __restrict__ out) {
  __shared__ short aT[64][32];
  __shared__ short bT[64][32];
  __shared__ float simf[5120];
  __shared__ float sqrow[64];

  const int t = threadIdx.x;
  const int lane = t & 63, wid = t >> 6;
  const int wr = wid >> 1, wc = wid & 1;
  const int fr = lane & 15, kg = lane >> 4;
  const int brow = blockIdx.x * 64;

  {
    f32x4* o4 = (f32x4*)(out + (size_t)brow * NROWS);
    const int total4 = 64 * NROWS / 4;
    f32x4 z = {0.f, 0.f, 0.f, 0.f};
    for (int i = t; i < total4; i += 256) o4[i] = z;
  }
  if (t < 64) sqrow[t] = sq[brow + t];

  float tv[10]; int ti[10];
#pragma unroll
  for (int s = 0; s < 10; ++s) { tv[s] = -INFINITY; ti[s] = 0x7fffffff; }
  const int sstage_r = t >> 2;
  const int sstage_k = (t & 3) * 8;

  for (int ctile = 0; ctile < NROWS / 64; ++ctile) {
    const int bcol = ctile * 64;
    f32x4 acc[2][2];
#pragma unroll
    for (int m = 0; m < 2; ++m)
#pragma unroll
      for (int n = 0; n < 2; ++n)
#pragma unroll
        for (int q = 0; q < 4; ++q) acc[m][n][q] = 0.f;

    for (int kt = 0; kt < DIM; kt += 32) {
      *(s16x8*)&aT[sstage_r][sstage_k] =
          *(const s16x8*)&fbf[(size_t)(brow + sstage_r) * DIM + kt + sstage_k];
      *(s16x8*)&bT[sstage_r][sstage_k] =
          *(const s16x8*)&fbf[(size_t)(bcol + sstage_r) * DIM + kt + sstage_k];
      __syncthreads();
      s16x8 a0 = *(const s16x8*)&aT[wr * 32 + fr][kg * 8];
      s16x8 a1 = *(const s16x8*)&aT[wr * 32 + 16 + fr][kg * 8];
      s16x8 b0 = *(const s16x8*)&bT[wc * 32 + fr][kg * 8];
      s16x8 b1 = *(const s16x8*)&bT[wc * 32 + 16 + fr][kg * 8];
      acc[0][0] = __builtin_amdgcn_mfma_f32_16x16x32_bf16(a0, b0, acc[0][0], 0, 0, 0);
      acc[0][1] = __builtin_amdgcn_mfma_f32_16x16x32_bf16(a0, b1, acc[0][1], 0, 0, 0);
      acc[1][0] = __builtin_amdgcn_mfma_f32_16x16x32_bf16(a1, b0, acc[1][0], 0, 0, 0);
      acc[1][1] = __builtin_amdgcn_mfma_f32_16x16x32_bf16(a1, b1, acc[1][1], 0, 0, 0);
      __syncthreads();
    }
#pragma unroll
    for (int m = 0; m < 2; ++m)
#pragma unroll
      for (int n = 0; n < 2; ++n)
#pragma unroll
        for (int q = 0; q < 4; ++q) {
          int rl = wr * 32 + m * 16 + kg * 4 + q;
          int cl = wc * 32 + n * 16 + fr;
          float dist = sqrow[rl] + sq[bcol + cl] - 2.0f * acc[m][n][q];
          float sv = ((brow + rl) == (bcol + cl)) ? 0.0f : __expf(-fmaxf(dist, 0.0f));
          simf[rl * 65 + cl] = sv;
        }
    __syncthreads();
    {
      const int c0 = wid * 16;
#pragma unroll
      for (int c = 0; c < 16; ++c) {
        float v = simf[lane * 65 + c0 + c];
        TOPK_INSERT(tv, ti, v, bcol + c0 + c);
      }
    }
    __syncthreads();
  }
#pragma unroll
  for (int s = 0; s < 10; ++s) {
    simf[(lane * 4 + wid) * 20 + s * 2]     = tv[s];
    simf[(lane * 4 + wid) * 20 + s * 2 + 1] = __int_as_float(ti[s]);
  }
  __syncthreads();
  if (t < 64) {
    float mv[10]; int mi[10];
#pragma unroll
    for (int s = 0; s < 10; ++s) { mv[s] = -INFINITY; mi[s] = 0x7fffffff; }
#pragma unroll
    for (int p = 0; p < 4; ++p)
#pragma unroll
      for (int s = 0; s < 10; ++s) {
        float v = simf[(t * 4 + p) * 20 + s * 2];
        int idx = __float_as_int(simf[(t * 4 + p) * 20 + s * 2 + 1]);
        TOPK_INSERT(mv, mi, v, idx);
      }
    float* orow = out + (size_t)(brow + t) * NROWS;
#pragma unroll
    for (int s = 0; s < 10; ++s) orow[mi[s]] = 1.0f;
  }
}

extern "C" void kernel_launch(void* const* d_in, const int* in_sizes, int n_in,
                              void* d_out, int out_size, void* d_ws, size_t ws_size,
                              hipStream_t stream) {
  const float* f = (const float*)d_in[0];
  float* out = (float*)d_out;

  const size_t sq_bytes   = (size_t)NROWS * sizeof(float);          // 49152
  const size_t fbf_bytes  = (size_t)NROWS * DIM * sizeof(unsigned short);
  const size_t part_bytes = (size_t)NROWS * NC * 10 * sizeof(float2);

  float* sq = (float*)d_ws;
  unsigned short* fbf = (unsigned short*)((char*)d_ws + sq_bytes);
  float2* part = (float2*)((char*)d_ws + sq_bytes + fbf_bytes);

  if (ws_size >= sq_bytes + fbf_bytes + part_bytes) {
    prep_kernel<<<NROWS / 4, 256, 0, stream>>>(f, sq, fbf);
    gram_topk<<<dim3(NRB, NC), 256, 0, stream>>>(fbf, sq, part, out);
    merge_scatter<<<NROWS / 128, 256, 0, stream>>>(part, out);
  } else if (ws_size >= sq_bytes + fbf_bytes) {
    prep_kernel<<<NROWS / 4, 256, 0, stream>>>(f, sq, fbf);
    knn_fallback<<<NROWS / 64, 256, 0, stream>>>(fbf, sq, out);
  }
}

// Round 15
// 487.319 us; speedup vs baseline: 4.3550x; 1.1798x over previous
//
#include <hip/hip_runtime.h>
#include <hip/hip_bf16.h>
#include <stdint.h>

#define NROWS 12288
#define DIM   512
#define KNBR  10

#define NC    8            // column chunks
#define CHUNK (NROWS / NC) // 1536
#define BT    64           // tile rows
#define BNT   128          // tile cols
#define CT    (CHUNK / BNT)// 12 col-tiles per block
#define NRB   (NROWS / BT) // 192 row blocks
#define KS    32           // K per pipeline step
#define KST   (DIM / KS)   // 16 k-steps

// exp(-x) == +0.0f (round-nearest) for all x >= 104 (exp(-104) < 2^-150).
#define UNDERFLOW_DIST 104.0f

typedef __attribute__((ext_vector_type(8))) short s16x8;
typedef __attribute__((ext_vector_type(4))) float f32x4;
typedef unsigned int u32;

static __device__ __forceinline__ unsigned short f2bf(float x) {
  __hip_bfloat16 b = __float2bfloat16(x);
  return *reinterpret_cast<unsigned short*>(&b);
}

static __device__ __forceinline__ void gload16(const void* g, void* l) {
  __builtin_amdgcn_global_load_lds(
      (const __attribute__((address_space(1))) u32*)g,
      (__attribute__((address_space(3))) u32*)l, 16, 0, 0);
}

// Stable top-k insert: keeps list sorted by (value desc, index asc).
#define TOPK_INSERT(TV, TI, V, IDX)                                              \
  do {                                                                           \
    float _v = (V); int _i = (IDX);                                              \
    if (_v > TV[9] || (_v == TV[9] && _i < TI[9])) {                             \
      TV[9] = _v; TI[9] = _i;                                                    \
      _Pragma("unroll")                                                          \
      for (int _s = 9; _s > 0; --_s) {                                           \
        bool _sw = (TV[_s] > TV[_s-1]) ||                                        \
                   (TV[_s] == TV[_s-1] && TI[_s] < TI[_s-1]);                    \
        if (_sw) {                                                               \
          float _tf = TV[_s]; TV[_s] = TV[_s-1]; TV[_s-1] = _tf;                 \
          int   _ti = TI[_s]; TI[_s] = TI[_s-1]; TI[_s-1] = _ti;                 \
        }                                                                        \
      }                                                                          \
    }                                                                            \
  } while (0)

// ---------------- Kernel 1: norms + bf16 conversion ----------------
__global__ __launch_bounds__(256) void prep_kernel(
    const float* __restrict__ f, float* __restrict__ sq,
    unsigned short* __restrict__ fbf) {
  const int wid = threadIdx.x >> 6;
  const int lane = threadIdx.x & 63;
  const int row = blockIdx.x * 4 + wid;
  const float4* fr = (const float4*)(f + (size_t)row * DIM);
  ushort4* br = (ushort4*)(fbf + (size_t)row * DIM);
  float s = 0.f;
#pragma unroll
  for (int u = 0; u < 2; ++u) {
    float4 v = fr[u * 64 + lane];
    s += v.x * v.x + v.y * v.y + v.z * v.z + v.w * v.w;
    ushort4 h;
    h.x = f2bf(v.x); h.y = f2bf(v.y); h.z = f2bf(v.z); h.w = f2bf(v.w);
    br[u * 64 + lane] = h;
  }
#pragma unroll
  for (int off = 32; off; off >>= 1) s += __shfl_down(s, off);
  if (lane == 0) sq[row] = s;
}

// ---------------- Kernel 2: 64x128 tile, acc[2][4], 3-buffer pipeline -------
// grid (192, 8). r14's verified counted-vmcnt pipeline with DOUBLE the work
// per step: wave sub-tile 32x64 -> acc[2][4] (32 VGPR, the spill-free acc
// budget), 8 MFMA : 6 ds_read per step (r14 was 4:4), and half the steps
// (12 tiles of 128 cols vs 24 of 64). r14 showed sync overhead is NOT the
// bound (counted vmcnt ~= drain-0); the per-step latency chain is -> amortize
// it over 2x arithmetic. STAGE = 3 gload16 -> in-loop wait is vmcnt(3).
// Swizzle identical to r14 (row-period-4; B rows wc*64+n*16+fr have the same
// (fr>>1)&3 term since n*8 = 0 mod 4 -- enumerated).
__global__ __launch_bounds__(256) void gram_topk(
    const unsigned short* __restrict__ fbf, const float* __restrict__ sq,
    float2* __restrict__ part, float* __restrict__ out) {
  // smem: A slices @0,4096,8192 (64x64B each); B slices @12288,20480,28672
  // (128x64B each) = 36KB. simf [64][130] f32 (33280B) and the merge dump
  // (20480B) overlay the slices (dead at those points).
  __shared__ __align__(16) char smem[36864];
  __shared__ float sqrow[BT];
  __shared__ float sqcs[BNT];
  float* simf = (float*)smem;

  const int t = threadIdx.x;
  const int lane = t & 63, wid = t >> 6;
  const int wr = wid >> 1, wc = wid & 1;      // wave -> 32-row half, 64-col half
  const int fr = lane & 15, kg = lane >> 4;   // MFMA fragment coords
  const int brow = blockIdx.x * BT;
  const int chunk = blockIdx.y;

  // Zero-fill this block's 1/1536 slice of the output.
  {
    const int bid = blockIdx.y * NRB + blockIdx.x;         // 0..1535
    const int per = NROWS * NROWS / (NRB * NC) / 4;        // f32x4 per block
    f32x4* o4 = (f32x4*)out + (size_t)bid * per;
    f32x4 z = {0.f, 0.f, 0.f, 0.f};
    for (int i = t; i < per; i += 256) o4[i] = z;
  }
  if (t < BT) sqrow[t] = sq[brow + t];

  float tv[10]; int ti[10];
#pragma unroll
  for (int s = 0; s < 10; ++s) { tv[s] = -INFINITY; ti[s] = 0x7fffffff; }

  // staging: rows are 64B (4 x 16B slots); chunk c: row=c>>2, slot=c&3, holds
  // source k-group slot^((row>>1)&3). A slice = 256 chunks (1 gload/thread),
  // B slice = 512 chunks (2 gloads/thread; rows +64 keep the same XOR term).
  const int srow0 = t >> 2;
  const size_t gOff = (size_t)srow0 * DIM + (((t & 3) ^ ((srow0 >> 1) & 3)) * 8);
  const int dB = wid * 1024;   // wave-uniform LDS base (+lane*16 by HW)
  const unsigned short* arow = fbf + (size_t)brow * DIM;
  // fragment read slot: kgroup kg stored at slot kg^((row>>1)&3); for all
  // fragment rows (wr*32+fr, +16; wc*64+n*16+fr) ((row>>1)&3) == ((fr>>1)&3).
  const int slotx = (kg ^ ((fr >> 1) & 3)) * 16;

  for (int ct = 0; ct < CT; ++ct) {
    const int bcol = chunk * CHUNK + ct * BNT;
    const unsigned short* bp = fbf + (size_t)bcol * DIM;
    if (t < BNT) sqcs[t] = sq[bcol + t];  // oldest vmem op; drained by vmcnt(3)

    f32x4 acc[2][4];
#pragma unroll
    for (int m = 0; m < 2; ++m)
#pragma unroll
      for (int n = 0; n < 4; ++n)
#pragma unroll
        for (int q = 0; q < 4; ++q) acc[m][n][q] = 0.f;

#define STAGE(KT, BUF)                                                       \
    do {                                                                     \
      gload16(arow + (KT) + gOff, smem + (BUF) * 4096 + dB);                 \
      gload16(bp + (KT) + gOff, smem + 12288 + (BUF) * 8192 + dB);           \
      gload16(bp + (KT) + gOff + 64 * DIM,                                   \
              smem + 12288 + (BUF) * 8192 + 4096 + dB);                      \
    } while (0)

    STAGE(0, 0);
    STAGE(KS, 1);
    asm volatile("s_waitcnt vmcnt(3)" ::: "memory");  // slice 0 + sq landed
    __builtin_amdgcn_s_barrier();                      // ... for every wave
    __builtin_amdgcn_sched_barrier(0);

#pragma unroll
    for (int k = 0; k < KST; ++k) {
      const char* ab = smem + (k % 3) * 4096;
      const char* bb = smem + 12288 + (k % 3) * 8192;
      s16x8 a0 = *(const s16x8*)(ab + (wr * 32 + fr) * 64 + slotx);
      s16x8 a1 = *(const s16x8*)(ab + (wr * 32 + 16 + fr) * 64 + slotx);
      s16x8 b[4];
#pragma unroll
      for (int n = 0; n < 4; ++n)
        b[n] = *(const s16x8*)(bb + (wc * 64 + n * 16 + fr) * 64 + slotx);
#pragma unroll
      for (int n = 0; n < 4; ++n) {
        acc[0][n] = __builtin_amdgcn_mfma_f32_16x16x32_bf16(a0, b[n], acc[0][n], 0, 0, 0);
        acc[1][n] = __builtin_amdgcn_mfma_f32_16x16x32_bf16(a1, b[n], acc[1][n], 0, 0, 0);
      }
      if (k < KST - 2) {
        STAGE((k + 2) * KS, (k + 2) % 3);   // overwrites buf((k-1)%3): safe
        asm volatile("s_waitcnt vmcnt(3)" ::: "memory");  // STAGE(k+1) landed
      } else {
        asm volatile("s_waitcnt vmcnt(0)" ::: "memory");  // tail: drain all
      }
      __builtin_amdgcn_s_barrier();
      __builtin_amdgcn_sched_barrier(0);
    }
#undef STAGE

    // Per-thread column norms (4 distinct cols), register-hoisted.
    float sqcn[4];
#pragma unroll
    for (int n = 0; n < 4; ++n) sqcn[n] = sqcs[wc * 64 + n * 16 + fr];

    // Underflow vote: any dist < 104 in this 64x128 tile?
    bool under = (ct > 0);
#pragma unroll
    for (int m = 0; m < 2; ++m)
#pragma unroll
      for (int n = 0; n < 4; ++n)
#pragma unroll
        for (int q = 0; q < 4; ++q) {
          const int rl = wr * 32 + m * 16 + kg * 4 + q;
          const float dist = sqrow[rl] + sqcn[n] - 2.0f * acc[m][n][q];
          under = under && (dist >= UNDERFLOW_DIST);
        }
    const int skip = __syncthreads_and((int)under);  // block-uniform

    if (!skip) {
      // Full epilogue (rare): dist -> sim, LDS tile (overlays slices), scan.
#pragma unroll
      for (int m = 0; m < 2; ++m)
#pragma unroll
        for (int n = 0; n < 4; ++n)
#pragma unroll
          for (int q = 0; q < 4; ++q) {
            int rl = wr * 32 + m * 16 + kg * 4 + q;
            int cl = wc * 64 + n * 16 + fr;
            float dist = sqrow[rl] + sqcn[n] - 2.0f * acc[m][n][q];
            float sv = ((brow + rl) == (bcol + cl)) ? 0.0f
                       : __expf(-fmaxf(dist, 0.0f));
            simf[rl * 130 + cl] = sv;
          }
      __syncthreads();
      {
        const int c0 = wid * 32;   // wave wid scans its 32-col sub-slice
#pragma unroll
        for (int c = 0; c < 32; ++c) {
          float v = simf[lane * 130 + c0 + c];
          TOPK_INSERT(tv, ti, v, bcol + c0 + c);
        }
      }
      __syncthreads();   // scan done before slices are re-staged next ct
    }
  }

  // Dump 4 partial lists per row, merge (thread t<64 owns row brow+t),
  // write the row's chunk top-10 to the workspace.
#pragma unroll
  for (int s = 0; s < 10; ++s) {
    simf[(lane * 4 + wid) * 20 + s * 2]     = tv[s];
    simf[(lane * 4 + wid) * 20 + s * 2 + 1] = __int_as_float(ti[s]);
  }
  __syncthreads();
  if (t < BT) {
    float mv[10]; int mi[10];
#pragma unroll
    for (int s = 0; s < 10; ++s) { mv[s] = -INFINITY; mi[s] = 0x7fffffff; }
#pragma unroll
    for (int p = 0; p < 4; ++p)
#pragma unroll
      for (int s = 0; s < 10; ++s) {
        float v = simf[(t * 4 + p) * 20 + s * 2];
        int idx = __float_as_int(simf[(t * 4 + p) * 20 + s * 2 + 1]);
        TOPK_INSERT(mv, mi, v, idx);
      }
    float2* dst = part + ((size_t)(brow + t) * NC + chunk) * 10;
#pragma unroll
    for (int s = 0; s < 10; ++s) dst[s] = make_float2(mv[s], __int_as_float(mi[s]));
  }
}

// ---------------- Kernel 3: merge NC chunk lists per row, scatter ones ------
__global__ __launch_bounds__(256) void merge_scatter(
    const float2* __restrict__ part, float* __restrict__ out) {
  const int t = threadIdx.x;
  if (t >= 128) return;
  const int r = blockIdx.x * 128 + t;
  float mv[10]; int mi[10];
#pragma unroll
  for (int s = 0; s < 10; ++s) { mv[s] = -INFINITY; mi[s] = 0x7fffffff; }
  const float2* p = part + (size_t)r * NC * 10;
#pragma unroll
  for (int c = 0; c < NC * 10; ++c)
    TOPK_INSERT(mv, mi, p[c].x, __float_as_int(p[c].y));
  float* orow = out + (size_t)r * NROWS;
#pragma unroll
  for (int s = 0; s < 10; ++s) orow[mi[s]] = 1.0f;
}

// ---------------- Fallback (round-1 single-kernel path, 12.6 MB ws) ---------
__global__ __launch_bounds__(256) void knn_fallback(
    const unsigned short* __restrict__ fbf, const float* __restrict__ sq,
    float* __restrict__ out) {
  __shared__ short aT[64][32];
  __shared__ short bT[64][32];
  __shared__ float simf[5120];
  __shared__ float sqrow[64];

  const int t = threadIdx.x;
  const int lane = t & 63, wid = t >> 6;
  const int wr = wid >> 1, wc = wid & 1;
  const int fr = lane & 15, kg = lane >> 4;
  const int brow = blockIdx.x * 64;

  {
    f32x4* o4 = (f32x4*)(out + (size_t)brow * NROWS);
    const int total4 = 64 * NROWS / 4;
    f32x4 z = {0.f, 0.f, 0.f, 0.f};
    for (int i = t; i < total4; i += 256) o4[i] = z;
  }
  if (t < 64) sqrow[t] = sq[brow + t];

  float tv[10]; int ti[10];
#pragma unroll
  for (int s = 0; s < 10; ++s) { tv[s] = -INFINITY; ti[s] = 0x7fffffff; }
  const int sstage_r = t >> 2;
  const int sstage_k = (t & 3) * 8;

  for (int ctile = 0; ctile < NROWS / 64; ++ctile) {
    const int bcol = ctile * 64;
    f32x4 acc[2][2];
#pragma unroll
    for (int m = 0; m < 2; ++m)
#pragma unroll
      for (int n = 0; n < 2; ++n)
#pragma unroll
        for (int q = 0; q < 4; ++q) acc[m][n][q] = 0.f;

    for (int kt = 0; kt < DIM; kt += 32) {
      *(s16x8*)&aT[sstage_r][sstage_k] =
          *(const s16x8*)&fbf[(size_t)(brow + sstage_r) * DIM + kt + sstage_k];
      *(s16x8*)&bT[sstage_r][sstage_k] =
          *(const s16x8*)&fbf[(size_t)(bcol + sstage_r) * DIM + kt + sstage_k];
      __syncthreads();
      s16x8 a0 = *(const s16x8*)&aT[wr * 32 + fr][kg * 8];
      s16x8 a1 = *(const s16x8*)&aT[wr * 32 + 16 + fr][kg * 8];
      s16x8 b0 = *(const s16x8*)&bT[wc * 32 + fr][kg * 8];
      s16x8 b1 = *(const s16x8*)&bT[wc * 32 + 16 + fr][kg * 8];
      acc[0][0] = __builtin_amdgcn_mfma_f32_16x16x32_bf16(a0, b0, acc[0][0], 0, 0, 0);
      acc[0][1] = __builtin_amdgcn_mfma_f32_16x16x32_bf16(a0, b1, acc[0][1], 0, 0, 0);
      acc[1][0] = __builtin_amdgcn_mfma_f32_16x16x32_bf16(a1, b0, acc[1][0], 0, 0, 0);
      acc[1][1] = __builtin_amdgcn_mfma_f32_16x16x32_bf16(a1, b1, acc[1][1], 0, 0, 0);
      __syncthreads();
    }
#pragma unroll
    for (int m = 0; m < 2; ++m)
#pragma unroll
      for (int n = 0; n < 2; ++n)
#pragma unroll
        for (int q = 0; q < 4; ++q) {
          int rl = wr * 32 + m * 16 + kg * 4 + q;
          int cl = wc * 32 + n * 16 + fr;
          float dist = sqrow[rl] + sq[bcol + cl] - 2.0f * acc[m][n][q];
          float sv = ((brow + rl) == (bcol + cl)) ? 0.0f : __expf(-fmaxf(dist, 0.0f));
          simf[rl * 65 + cl] = sv;
        }
    __syncthreads();
    {
      const int c0 = wid * 16;
#pragma unroll
      for (int c = 0; c < 16; ++c) {
        float v = simf[lane * 65 + c0 + c];
        TOPK_INSERT(tv, ti, v, bcol + c0 + c);
      }
    }
    __syncthreads();
  }
#pragma unroll
  for (int s = 0; s < 10; ++s) {
    simf[(lane * 4 + wid) * 20 + s * 2]     = tv[s];
    simf[(lane * 4 + wid) * 20 + s * 2 + 1] = __int_as_float(ti[s]);
  }
  __syncthreads();
  if (t < 64) {
    float mv[10]; int mi[10];
#pragma unroll
    for (int s = 0; s < 10; ++s) { mv[s] = -INFINITY; mi[s] = 0x7fffffff; }
#pragma unroll
    for (int p = 0; p < 4; ++p)
#pragma unroll
      for (int s = 0; s < 10; ++s) {
        float v = simf[(t * 4 + p) * 20 + s * 2];
        int idx = __float_as_int(simf[(t * 4 + p) * 20 + s * 2 + 1]);
        TOPK_INSERT(mv, mi, v, idx);
      }
    float* orow = out + (size_t)(brow + t) * NROWS;
#pragma unroll
    for (int s = 0; s < 10; ++s) orow[mi[s]] = 1.0f;
  }
}

extern "C" void kernel_launch(void* const* d_in, const int* in_sizes, int n_in,
                              void* d_out, int out_size, void* d_ws, size_t ws_size,
                              hipStream_t stream) {
  const float* f = (const float*)d_in[0];
  float* out = (float*)d_out;

  const size_t sq_bytes   = (size_t)NROWS * sizeof(float);          // 49152
  const size_t fbf_bytes  = (size_t)NROWS * DIM * sizeof(unsigned short);
  const size_t part_bytes = (size_t)NROWS * NC * 10 * sizeof(float2);

  float* sq = (float*)d_ws;
  unsigned short* fbf = (unsigned short*)((char*)d_ws + sq_bytes);
  float2* part = (float2*)((char*)d_ws + sq_bytes + fbf_bytes);

  if (ws_size >= sq_bytes + fbf_bytes + part_bytes) {
    prep_kernel<<<NROWS / 4, 256, 0, stream>>>(f, sq, fbf);
    gram_topk<<<dim3(NRB, NC), 256, 0, stream>>>(fbf, sq, part, out);
    merge_scatter<<<NROWS / 128, 256, 0, stream>>>(part, out);
  } else if (ws_size >= sq_bytes + fbf_bytes) {
    prep_kernel<<<NROWS / 4, 256, 0, stream>>>(f, sq, fbf);
    knn_fallback<<<NROWS / 64, 256, 0, stream>>>(fbf, sq, out);
  }
}